// Round 11
// baseline (207.490 us; speedup 1.0000x reference)
//
#include <hip/hip_runtime.h>
#include <hip/hip_bf16.h>

// GraphSAGE 2-layer, fused per-block {gather+mean -> LDS} then {MFMA GEMM}.
// Round 11: template<ROWS> (64 for L1, 32 for L2-spread); 1-ahead index prefetch
// in gather; sched_barrier(0)-pinned B-prefetch in GEMM.
// N_RAW=200000, N1=100000, N2=20000, D=256, OUT=256.

typedef __attribute__((ext_vector_type(8))) short bf16x8;
typedef __attribute__((ext_vector_type(4))) float f32x4;

static __device__ __forceinline__ short f2bf(float f) {
  __hip_bfloat16 h = __float2bfloat16(f);
  return *reinterpret_cast<short*>(&h);
}
static __device__ __forceinline__ float bf2f(short s) {
  union { unsigned u; float f; } x;
  x.u = ((unsigned)(unsigned short)s) << 16;
  return x.f;
}

// ---------------- one-shot f32 -> bf16: raw (25000 blocks) + W1 (64) + W2 (64) ----------------
// NT loads: don't pollute L2/LLC with the 205 MB f32 stream; rawb stays LLC-resident.
__global__ __launch_bounds__(256) void convert_all(
    const float* __restrict__ raw, const float* __restrict__ W1,
    const float* __restrict__ W2, short* __restrict__ rawb,
    short* __restrict__ W1b, short* __restrict__ W2b) {
  const int b = blockIdx.x;
  const float* src;
  short* dst;
  size_t base;
  if (b < 25000) { src = raw; dst = rawb; base = (size_t)b * 2048; }
  else if (b < 25064) { src = W1; dst = W1b; base = (size_t)(b - 25000) * 2048; }
  else { src = W2; dst = W2b; base = (size_t)(b - 25064) * 2048; }
  const size_t i = base + (size_t)threadIdx.x * 8;
  const f32x4* s4 = reinterpret_cast<const f32x4*>(src + i);
  f32x4 u = __builtin_nontemporal_load(s4);
  f32x4 v = __builtin_nontemporal_load(s4 + 1);
  bf16x8 o;
  o[0] = f2bf(u.x); o[1] = f2bf(u.y); o[2] = f2bf(u.z); o[3] = f2bf(u.w);
  o[4] = f2bf(v.x); o[5] = f2bf(v.y); o[6] = f2bf(v.z); o[7] = f2bf(v.w);
  *reinterpret_cast<bf16x8*>(dst + i) = o;
}

// ---------------- fused layer: gather+mean -> LDS -> relu(comb @ W^T) ----------------
// Block: ROWS x 256, 512 threads (8 waves).
// Gather: thread (c=tid&31 chunk, rs=tid>>5 slot 0..15) does rows rs*RPT..+RPT-1,
//         with next row's indices prefetched one step ahead.
// GEMM: wave w -> cols w*32..+31; ROWS/16 m-frags x 2 n-frags;
//       B-prefetch pinned before the MFMA cluster by sched_barrier(0).
template <int ROWS, bool OUT_BF16>
__global__ __launch_bounds__(512, 4) void sage_fused(
    const short* __restrict__ E,        // [Ne][256] bf16 embeddings
    const int* __restrict__ self_idx,   // [Nv]
    const int* __restrict__ neigh,      // [Nv][10]
    const short* __restrict__ Wb,       // [256][512] bf16 (W row-major)
    void* __restrict__ out,             // [Nv][256] (bf16 or f32)
    int Nvalid) {
  __shared__ short As[ROWS][520];  // row stride 1040 B
  constexpr int RPT = ROWS / 16;   // serial rows per thread (16 row-slots)
  constexpr int MF = ROWS / 16;    // m-frags per wave

  const int tid = threadIdx.x;
  const int m0 = blockIdx.x * ROWS;
  const int c = tid & 31;    // 16-B chunk (8 bf16) within 256-col row
  const int rs = tid >> 5;   // row slot 0..15

  // ---- gather + mean with 1-ahead index prefetch ----
  {
    int nbx[2][10];
    int six[2];
    {
      int gr = m0 + rs * RPT;
      gr = gr < Nvalid ? gr : Nvalid - 1;
#pragma unroll
      for (int k = 0; k < 10; ++k) nbx[0][k] = neigh[gr * 10 + k];
      six[0] = self_idx[gr];
    }
#pragma unroll
    for (int rr = 0; rr < RPT; ++rr) {
      const int cur = rr & 1, nxt = cur ^ 1;
      if (rr + 1 < RPT) {  // prefetch next row's indices (hidden under this row)
        int gr = m0 + rs * RPT + rr + 1;
        gr = gr < Nvalid ? gr : Nvalid - 1;
#pragma unroll
        for (int k = 0; k < 10; ++k) nbx[nxt][k] = neigh[gr * 10 + k];
        six[nxt] = self_idx[gr];
      }
      bf16x8 sv = *reinterpret_cast<const bf16x8*>(
          E + (size_t)(unsigned)six[cur] * 256 + c * 8);
      bf16x8 v[10];
#pragma unroll
      for (int k = 0; k < 10; ++k)
        v[k] = *reinterpret_cast<const bf16x8*>(
            E + (size_t)(unsigned)nbx[cur][k] * 256 + c * 8);
      bf16x8 mv;
#pragma unroll
      for (int j = 0; j < 8; ++j) {
        float sA = bf2f(v[0][j]) + bf2f(v[2][j]) + bf2f(v[4][j]) + bf2f(v[6][j]) + bf2f(v[8][j]);
        float sB = bf2f(v[1][j]) + bf2f(v[3][j]) + bf2f(v[5][j]) + bf2f(v[7][j]) + bf2f(v[9][j]);
        mv[j] = f2bf((sA + sB) * 0.1f);
      }
      const int r = rs * RPT + rr;
      *reinterpret_cast<bf16x8*>(&As[r][c * 8]) = sv;
      *reinterpret_cast<bf16x8*>(&As[r][256 + c * 8]) = mv;
    }
  }
  __syncthreads();

  // ---- GEMM phase: ROWS x 256 = 8 waves x (ROWS x 32), K=512 ----
  const int wave = tid >> 6, lane = tid & 63;
  const int wn = wave * 32;
  const int lr = lane & 15;           // m (A) / n (B) within 16x16 frag
  const int lkb = (lane >> 4) * 8;    // k base within 32
  const short* Bp = Wb + (size_t)(wn + lr) * 512 + lkb;  // + nf*8192 + ks*32

  f32x4 acc[MF][2] = {};

  bf16x8 b0 = *reinterpret_cast<const bf16x8*>(Bp);
  bf16x8 b1 = *reinterpret_cast<const bf16x8*>(Bp + 8192);

#pragma unroll
  for (int ks = 0; ks < 16; ++ks) {
    bf16x8 nb0 = b0, nb1 = b1;
    if (ks < 15) {
      nb0 = *reinterpret_cast<const bf16x8*>(Bp + (ks + 1) * 32);
      nb1 = *reinterpret_cast<const bf16x8*>(Bp + (ks + 1) * 32 + 8192);
    }
    // pin the prefetch issue before the MFMA cluster (compiler may not sink it)
    __builtin_amdgcn_sched_barrier(0);
    bf16x8 a[MF];
#pragma unroll
    for (int mi = 0; mi < MF; ++mi)
      a[mi] = *reinterpret_cast<const bf16x8*>(&As[mi * 16 + lr][ks * 32 + lkb]);
    __builtin_amdgcn_s_setprio(1);
#pragma unroll
    for (int mi = 0; mi < MF; ++mi) {
      acc[mi][0] = __builtin_amdgcn_mfma_f32_16x16x32_bf16(a[mi], b0, acc[mi][0], 0, 0, 0);
      acc[mi][1] = __builtin_amdgcn_mfma_f32_16x16x32_bf16(a[mi], b1, acc[mi][1], 0, 0, 0);
    }
    __builtin_amdgcn_s_setprio(0);
    b0 = nb0; b1 = nb1;
  }

  // ---- epilogue: relu + store (C/D: col=lane&15, row=(lane>>4)*4+reg) ----
#pragma unroll
  for (int mi = 0; mi < MF; ++mi)
#pragma unroll
    for (int ni = 0; ni < 2; ++ni)
#pragma unroll
      for (int r = 0; r < 4; ++r) {
        const int gm = m0 + mi * 16 + (lane >> 4) * 4 + r;
        const int gn = wn + ni * 16 + lr;
        float v = acc[mi][ni][r];
        v = v > 0.f ? v : 0.f;
        if (gm < Nvalid) {
          if (OUT_BF16)
            reinterpret_cast<short*>(out)[(size_t)gm * 256 + gn] = f2bf(v);
          else
            reinterpret_cast<float*>(out)[(size_t)gm * 256 + gn] = v;
        }
      }
}

extern "C" void kernel_launch(void* const* d_in, const int* in_sizes, int n_in,
                              void* d_out, int out_size, void* d_ws, size_t ws_size,
                              hipStream_t stream) {
  const float* raw = (const float*)d_in[0];
  const float* W1 = (const float*)d_in[1];
  const float* W2 = (const float*)d_in[2];
  const int* nodes1 = (const int*)d_in[3];
  const int* neigh1 = (const int*)d_in[4];
  const int* self2 = (const int*)d_in[5];
  const int* neigh2 = (const int*)d_in[6];
  float* out = (float*)d_out;

  const int N_RAW = 200000, N1 = 100000, N2 = 20000;

  short* rawb = (short*)d_ws;                         // 200000*256 bf16 = 102.4 MB
  short* h1 = rawb + (size_t)N_RAW * 256;             // 100000*256 bf16 = 51.2 MB
  short* W1b = h1 + (size_t)N1 * 256;                 // 131072 bf16
  short* W2b = W1b + 131072;                          // 131072 bf16

  convert_all<<<25128, 256, 0, stream>>>(raw, W1, W2, rawb, W1b, W2b);
  sage_fused<64, true><<<(N1 + 63) / 64, 512, 0, stream>>>(rawb, nodes1, neigh1, W1b, h1, N1);
  sage_fused<32, false><<<(N2 + 31) / 32, 512, 0, stream>>>(h1, self2, neigh2, W2b, out, N2);
}